// Round 2
// baseline (256.518 us; speedup 1.0000x reference)
//
#include <hip/hip_runtime.h>
#include <hip/hip_bf16.h>

#define C_IN  64
#define C_OUT 128
#define KK    27
#define HH    100000
#define RS    68           // LDS row stride in shorts (64 + 4 pad)
#define TB    1563         // transpose blocks = ceil(HH/64)
#define WB    108          // weight-convert blocks (108*2048 = 221184 elems)

typedef __attribute__((ext_vector_type(8))) short s8v;    // 8 bf16 (MFMA A/B frag)
typedef __attribute__((ext_vector_type(4))) float f32x4;  // MFMA C/D frag

__device__ inline unsigned short f2bf(float f) {
    __hip_bfloat16 h = __float2bfloat16(f);
    return *reinterpret_cast<unsigned short*>(&h);
}

// ---------------- fused prep: transpose x -> xt (bf16), relayout W -> wk (bf16) ----
__global__ __launch_bounds__(256) void prep_kernel(const float* __restrict__ x,
                                                   const float* __restrict__ w,
                                                   unsigned short* __restrict__ xt,
                                                   unsigned short* __restrict__ wk) {
    const int tid = threadIdx.x;
    if (blockIdx.x < TB) {
        __shared__ __align__(16) unsigned short ts[64 * 72];
        const int hbase = blockIdx.x * 64;
        #pragma unroll
        for (int it = 0; it < 16; ++it) {
            int i = it * 256 + tid;           // 64h x 64c
            int c = i >> 6, hl = i & 63;
            int hg = hbase + hl;
            float v = (hg < HH) ? x[(size_t)c * HH + hg] : 0.f;  // coalesced in h
            ts[hl * 72 + c] = f2bf(v);
        }
        __syncthreads();
        #pragma unroll
        for (int it = 0; it < 2; ++it) {
            int u = it * 256 + tid;           // 64 rows x 8 chunks of 16B
            int hl = u >> 3, part = u & 7;
            int hg = hbase + hl;
            if (hg < HH)
                *(int4*)&xt[(size_t)hg * 64 + part * 8] = *(const int4*)&ts[hl * 72 + part * 8];
        }
    } else {
        int b = blockIdx.x - TB;
        int base = b * 2048 + tid;
        #pragma unroll
        for (int j = 0; j < 8; ++j) {
            int t = base + j * 256;           // wk order: t = k*8192 + o*64 + c
            int c = t & 63, o = (t >> 6) & 127, kx = t >> 13;
            wk[t] = f2bf(w[(size_t)o * (C_IN * KK) + c * KK + kx]);
        }
    }
}

// ---------------- main gather-GEMM, software-pipelined ----------------
// block: 256 thr = 4 waves; tile M=128 (all o) x N=128 h; wave w: h sub-tile [w*32, w*32+32)
__global__ __launch_bounds__(256) void conv_main(const unsigned short* __restrict__ xt,
                                                 const unsigned short* __restrict__ wk,
                                                 const int* __restrict__ neigh,
                                                 float* __restrict__ out) {
    __shared__ __align__(16) unsigned short w_s[128 * RS];   // 17408 B
    __shared__ __align__(16) unsigned short c_s[128 * RS];   // 17408 B

    const int tid  = threadIdx.x;
    const int wave = tid >> 6;
    const int lane = tid & 63;
    const int col  = lane & 15;
    const int quad = lane >> 4;
    const int nb   = wave * 32;
    const int hbase = blockIdx.x * 128;

    // gather roles: each thread owns 32B (part) of two columns (hl0, hl1)
    const int hl0  = tid >> 2, part = tid & 3;
    const int hl1  = 64 + hl0;
    const int hg0  = hbase + hl0, hg1 = hbase + hl1;
    const bool v0 = hg0 < HH, v1 = hg1 < HH;
    const size_t n0 = v0 ? (size_t)hg0 * KK : 0;
    const size_t n1 = v1 ? (size_t)hg1 * KK : 0;

    auto gather2 = [&](int idx, int4& a, int4& b) {
        if (idx >= 0) {
            const int4* s = (const int4*)(xt + (size_t)idx * 64 + part * 16);
            a = s[0]; b = s[1];
        } else {
            a = make_int4(0, 0, 0, 0); b = make_int4(0, 0, 0, 0);
        }
    };

    f32x4 acc[8][2];
    #pragma unroll
    for (int mt = 0; mt < 8; ++mt) {
        acc[mt][0] = (f32x4){0.f, 0.f, 0.f, 0.f};
        acc[mt][1] = (f32x4){0.f, 0.f, 0.f, 0.f};
    }

    // prologue: idx for k=0 and k=1; stage slice 0
    int iA1 = v0 ? neigh[n0 + 0] : -1;
    int iB1 = v1 ? neigh[n1 + 0] : -1;
    int iA2 = v0 ? neigh[n0 + 1] : -1;
    int iB2 = v1 ? neigh[n1 + 1] : -1;
    {
        const int4* ws = (const int4*)wk;   // slice 0 (16 KB contiguous)
        int4 wv[4];
        #pragma unroll
        for (int j = 0; j < 4; ++j) wv[j] = ws[j * 256 + tid];
        int4 ga0, ga1, gb0, gb1;
        gather2(iA1, ga0, ga1);
        gather2(iB1, gb0, gb1);
        #pragma unroll
        for (int j = 0; j < 4; ++j) {
            int i = j * 256 + tid; int o = i >> 3, cc = i & 7;
            *(int4*)&w_s[o * RS + cc * 8] = wv[j];
        }
        *(int4*)&c_s[hl0 * RS + part * 16]     = ga0;
        *(int4*)&c_s[hl0 * RS + part * 16 + 8] = ga1;
        *(int4*)&c_s[hl1 * RS + part * 16]     = gb0;
        *(int4*)&c_s[hl1 * RS + part * 16 + 8] = gb1;
        iA1 = iA2; iB1 = iB2;   // now iA1/iB1 hold idx for k=1
    }
    __syncthreads();

    #pragma unroll 1
    for (int k = 0; k < KK; ++k) {
        const bool more = (k + 1 < KK);
        int4 nwv[4], nga0, nga1, ngb0, ngb1;
        int niA = -1, niB = -1;
        if (more) {
            // prefetch W(k+1), gather(k+1), idx(k+2) — overlaps MFMA below
            const int4* ws = (const int4*)(wk + (size_t)(k + 1) * (C_OUT * C_IN));
            #pragma unroll
            for (int j = 0; j < 4; ++j) nwv[j] = ws[j * 256 + tid];
            gather2(iA1, nga0, nga1);
            gather2(iB1, ngb0, ngb1);
            int kc = (k + 2 < KK) ? (k + 2) : (KK - 1);
            niA = v0 ? neigh[n0 + kc] : -1;
            niB = v1 ? neigh[n1 + kc] : -1;
        }

        // MFMA on current LDS slice
        #pragma unroll
        for (int ch = 0; ch < 2; ++ch) {
            s8v b0 = *(const s8v*)&c_s[(nb + col) * RS + ch * 32 + quad * 8];
            s8v b1 = *(const s8v*)&c_s[(nb + 16 + col) * RS + ch * 32 + quad * 8];
            #pragma unroll
            for (int mt = 0; mt < 8; ++mt) {
                s8v a = *(const s8v*)&w_s[(mt * 16 + col) * RS + ch * 32 + quad * 8];
                acc[mt][0] = __builtin_amdgcn_mfma_f32_16x16x32_bf16(a, b0, acc[mt][0], 0, 0, 0);
                acc[mt][1] = __builtin_amdgcn_mfma_f32_16x16x32_bf16(a, b1, acc[mt][1], 0, 0, 0);
            }
        }

        if (more) {
            __syncthreads();   // all waves done reading slice k
            #pragma unroll
            for (int j = 0; j < 4; ++j) {
                int i = j * 256 + tid; int o = i >> 3, cc = i & 7;
                *(int4*)&w_s[o * RS + cc * 8] = nwv[j];
            }
            *(int4*)&c_s[hl0 * RS + part * 16]     = nga0;
            *(int4*)&c_s[hl0 * RS + part * 16 + 8] = nga1;
            *(int4*)&c_s[hl1 * RS + part * 16]     = ngb0;
            *(int4*)&c_s[hl1 * RS + part * 16 + 8] = ngb1;
            iA1 = niA; iB1 = niB;
            __syncthreads();   // slice k+1 visible
        }
    }

    // epilogue: D row = quad*4+reg (o), col = lane&15 (h); relu + fp32 store
    #pragma unroll
    for (int mt = 0; mt < 8; ++mt) {
        #pragma unroll
        for (int nt = 0; nt < 2; ++nt) {
            int hg = hbase + nb + nt * 16 + col;
            if (hg < HH) {
                #pragma unroll
                for (int r = 0; r < 4; ++r) {
                    int o = mt * 16 + quad * 4 + r;
                    float v = acc[mt][nt][r];
                    out[(size_t)o * HH + hg] = v > 0.f ? v : 0.f;
                }
            }
        }
    }
}

extern "C" void kernel_launch(void* const* d_in, const int* in_sizes, int n_in,
                              void* d_out, int out_size, void* d_ws, size_t ws_size,
                              hipStream_t stream) {
    const float* data_in = (const float*)d_in[0];
    const int*   neigh   = (const int*)d_in[1];
    const float* weight  = (const float*)d_in[2];
    float* out = (float*)d_out;

    unsigned short* xt = (unsigned short*)d_ws;            // H*64 bf16 = 12.8 MB
    unsigned short* wk = xt + (size_t)HH * 64;             // 27*128*64 bf16 = 442 KB

    prep_kernel<<<TB + WB, 256, 0, stream>>>(data_in, weight, xt, wk);
    conv_main<<<(HH + 127) / 128, 256, 0, stream>>>(xt, wk, neigh, out);
}

// Round 3
// 167.578 us; speedup vs baseline: 1.5307x; 1.5307x over previous
//
#include <hip/hip_runtime.h>
#include <hip/hip_bf16.h>

#define C_IN  64
#define C_OUT 128
#define KK    27
#define HH    100000
#define TB    1563         // transpose blocks = ceil(HH/64)
#define WB    108          // weight-convert blocks (108*2048 = 221184 elems)
#define NBLK  391          // ceil(HH/256)

typedef __attribute__((ext_vector_type(8))) short s8v;    // 8 bf16 (MFMA A/B frag)
typedef __attribute__((ext_vector_type(4))) float f32x4;  // MFMA C/D frag

__device__ inline unsigned short f2bf(float f) {
    __hip_bfloat16 h = __float2bfloat16(f);
    return *reinterpret_cast<unsigned short*>(&h);
}

__device__ inline void dma16(const void* g, void* l) {
    __builtin_amdgcn_global_load_lds((const __attribute__((address_space(1))) void*)g,
                                     (__attribute__((address_space(3))) void*)l, 16, 0, 0);
}

// ---- prep: transpose x -> xt (bf16, [h][64] plain), W -> wk (bf16, [k][o][64] XOR-swizzled) ----
// wk physical chunk pj (16B unit) holds logical chunk pj ^ (o&7).
__global__ __launch_bounds__(256) void prep_kernel(const float* __restrict__ x,
                                                   const float* __restrict__ w,
                                                   unsigned short* __restrict__ xt,
                                                   unsigned short* __restrict__ wk) {
    const int tid = threadIdx.x;
    if (blockIdx.x < TB) {
        __shared__ __align__(16) unsigned short ts[64 * 72];
        const int hbase = blockIdx.x * 64;
        #pragma unroll
        for (int it = 0; it < 16; ++it) {
            int i = it * 256 + tid;           // 64h x 64c
            int c = i >> 6, hl = i & 63;
            int hg = hbase + hl;
            float v = (hg < HH) ? x[(size_t)c * HH + hg] : 0.f;  // coalesced in h
            ts[hl * 72 + c] = f2bf(v);
        }
        __syncthreads();
        #pragma unroll
        for (int it = 0; it < 2; ++it) {
            int u = it * 256 + tid;           // 64 rows x 8 chunks of 16B
            int hl = u >> 3, part = u & 7;
            int hg = hbase + hl;
            if (hg < HH)
                *(int4*)&xt[(size_t)hg * 64 + part * 8] = *(const int4*)&ts[hl * 72 + part * 8];
        }
    } else {
        int b = blockIdx.x - TB;
        int base = b * 2048 + tid;
        #pragma unroll
        for (int j = 0; j < 8; ++j) {
            int t = base + j * 256;           // wk index: t = k*8192 + o*64 + jj
            int jj = t & 63, o = (t >> 6) & 127, kx = t >> 13;
            int lc = (jj >> 3) ^ (o & 7);     // logical chunk
            int c  = lc * 8 + (jj & 7);
            wk[t] = f2bf(w[(size_t)o * (C_IN * KK) + c * KK + kx]);
        }
    }
}

// ---------------- main gather-GEMM ----------------
// block 256 thr = 4 waves; tile M=128 (all o) x N=256 h; wave w: h strip [w*64, w*64+64)
// A (weights) via async DMA double-buffered LDS; B (gathered cols) direct global->VGPR, 1-iter prefetch.
__global__ __launch_bounds__(256, 2) void conv_main(const unsigned short* __restrict__ xt,
                                                    const unsigned short* __restrict__ wk,
                                                    const int* __restrict__ neigh,
                                                    float* __restrict__ out) {
    __shared__ int neigh_s[256 * KK];                            // 27648 B, [h][k]
    __shared__ __align__(16) unsigned short w_s[2][128 * 64];    // 2 x 16 KB, XOR-swizzled rows

    const int tid  = threadIdx.x;
    const int wave = tid >> 6;
    const int lane = tid & 63;
    const int col  = lane & 15;
    const int quad = lane >> 4;
    const int hbase = blockIdx.x * 256;

    // ---- stage neighbor indices (coalesced) ----
    #pragma unroll
    for (int j = 0; j < KK; ++j) {
        int i = j * 256 + tid;                // 6912 = 27*256 exactly
        int hl = i / KK, kx = i - hl * KK;
        int hg = hbase + hl;
        neigh_s[i] = (hg < HH) ? neigh[(size_t)hg * KK + kx] : -1;
    }

    // ---- issue W DMA for k=0 into buf 0 ----
    {
        const unsigned short* src = wk;       // slice 0
        #pragma unroll
        for (int i = 0; i < 4; ++i) {
            int row_base = wave * 8 + i * 32; // 8 rows = 1024 B per inst
            dma16(src + row_base * 64 + lane * 8, &w_s[0][row_base * 64]);
        }
    }

    f32x4 acc[8][4];
    #pragma unroll
    for (int mt = 0; mt < 8; ++mt)
        #pragma unroll
        for (int nt = 0; nt < 4; ++nt)
            acc[mt][nt] = (f32x4){0.f, 0.f, 0.f, 0.f};

    __syncthreads();   // neigh_s ready; drains DMA k=0 too

    // ---- B-fragment loader: 8 x 16B direct gathers into VGPRs ----
    int4 cur[2][4], nxt[2][4];
    const int pc_b = (quad * 8);              // element offset of quad's chunk within column
    auto loadB = [&](int kk, int4 (&frag)[2][4]) {
        #pragma unroll
        for (int nt = 0; nt < 4; ++nt) {
            int n = wave * 64 + nt * 16 + col;
            int idx = neigh_s[n * KK + kk];
            if (idx >= 0) {
                const unsigned short* base = xt + (size_t)idx * 64 + pc_b;
                frag[0][nt] = *(const int4*)(base);
                frag[1][nt] = *(const int4*)(base + 32);
            } else {
                frag[0][nt] = make_int4(0, 0, 0, 0);
                frag[1][nt] = make_int4(0, 0, 0, 0);
            }
        }
    };

    loadB(0, cur);

    int p = 0;
    #pragma unroll 1
    for (int k = 0; k < KK; ++k) {
        if (k + 1 < KK) {
            // async W DMA for k+1 into other buffer
            const unsigned short* src = wk + (size_t)(k + 1) * (C_OUT * C_IN);
            #pragma unroll
            for (int i = 0; i < 4; ++i) {
                int row_base = wave * 8 + i * 32;
                dma16(src + row_base * 64 + lane * 8, &w_s[p ^ 1][row_base * 64]);
            }
            loadB(k + 1, nxt);   // latency hidden under MFMA phase below
        }

        // MFMA phase on w_s[p] + cur
        #pragma unroll
        for (int ch = 0; ch < 2; ++ch) {
            const int pc = (ch * 4 + quad) ^ (col & 7);   // physical chunk (XOR swizzle)
            #pragma unroll
            for (int mt = 0; mt < 8; ++mt) {
                s8v a = *(const s8v*)&w_s[p][(mt * 16 + col) * 64 + pc * 8];
                #pragma unroll
                for (int nt = 0; nt < 4; ++nt) {
                    s8v b = __builtin_bit_cast(s8v, cur[ch][nt]);
                    acc[mt][nt] = __builtin_amdgcn_mfma_f32_16x16x32_bf16(a, b, acc[mt][nt], 0, 0, 0);
                }
            }
        }

        __syncthreads();   // drains DMA (k+1) + orders buffer swap across waves
        #pragma unroll
        for (int ch = 0; ch < 2; ++ch)
            #pragma unroll
            for (int nt = 0; nt < 4; ++nt)
                cur[ch][nt] = nxt[ch][nt];
        p ^= 1;
    }

    // ---- epilogue: D row = quad*4+r (o), col = lane&15 (h); relu + fp32 store ----
    #pragma unroll
    for (int mt = 0; mt < 8; ++mt) {
        #pragma unroll
        for (int nt = 0; nt < 4; ++nt) {
            int hg = hbase + wave * 64 + nt * 16 + col;
            if (hg < HH) {
                #pragma unroll
                for (int r = 0; r < 4; ++r) {
                    int o = mt * 16 + quad * 4 + r;
                    float v = acc[mt][nt][r];
                    out[(size_t)o * HH + hg] = v > 0.f ? v : 0.f;
                }
            }
        }
    }
}

extern "C" void kernel_launch(void* const* d_in, const int* in_sizes, int n_in,
                              void* d_out, int out_size, void* d_ws, size_t ws_size,
                              hipStream_t stream) {
    const float* data_in = (const float*)d_in[0];
    const int*   neigh   = (const int*)d_in[1];
    const float* weight  = (const float*)d_in[2];
    float* out = (float*)d_out;

    unsigned short* xt = (unsigned short*)d_ws;            // H*64 bf16 = 12.8 MB
    unsigned short* wk = xt + (size_t)HH * 64;             // 27*128*64 bf16 = 442 KB

    prep_kernel<<<TB + WB, 256, 0, stream>>>(data_in, weight, xt, wk);
    conv_main<<<NBLK, 256, 0, stream>>>(xt, wk, neigh, out);
}